// Round 1
// baseline (248.655 us; speedup 1.0000x reference)
//
#include <hip/hip_runtime.h>

// Gated delta-rule recurrent cell, single step.
// B=128, H=16, Dk=Dv=128. Grid = BH*4: each block owns a 128(k) x 32(v)
// column-slice of one (b,h) state tile. The algorithm decomposes per
// v-column (only k.q couples columns; recomputed per block from 1 KB LDS).
// Per-thread tile: 4 x float4 = 16 VGPRs -> truly register-resident across
// the barrier (previous version needed 64 VGPRs for the tile alone and the
// compiler rematerialized via L2 re-loads).
// out[v] = decay*Bq[v] + (k.q)*delta[v]  (algebraic identity, single pass)

#define DK 128
#define DV 128
#define VS 32              // v-slice width per block
typedef float f4 __attribute__((ext_vector_type(4)));

__global__ __launch_bounds__(256) void s1_cell_kernel(
    const float* __restrict__ q,
    const float* __restrict__ k,
    const float* __restrict__ v,
    const float* __restrict__ g,
    const float* __restrict__ beta,
    const float* __restrict__ S,
    float* __restrict__ out,      // full d_out
    int BH)
{
    const int bh    = blockIdx.x >> 2;
    const int sl    = blockIdx.x & 3;
    const int vbase = sl * VS;

    const size_t stile = (size_t)bh * DK * DV;
    const float* __restrict__ Sb   = S + stile + vbase;
    float* __restrict__ out_o      = out + (size_t)bh * DV + vbase;
    float* __restrict__ out_S      = out + (size_t)BH * DV + stile + vbase;

    __shared__ float kt[DK];
    __shared__ float qt[DK];
    __shared__ float vt[VS];
    __shared__ float apart[32][VS];   // partial S^T k, per 32 row-groups
    __shared__ float bpart[32][VS];   // partial S^T q
    __shared__ float sdelta[VS];
    __shared__ float s_kq;

    const int t = threadIdx.x;

    if (t < DK) {
        kt[t] = k[bh * DK + t];
        qt[t] = q[bh * DK + t];
    }
    if (t < VS) vt[t] = v[bh * DV + vbase + t];
    __syncthreads();

    const float decay = expf(g[bh]);
    const float bta   = beta[bh];

    // --- k.q reduction (wave 0) ---
    if (t < 64) {
        float val = kt[t] * qt[t] + kt[t + 64] * qt[t + 64];
        #pragma unroll
        for (int off = 32; off > 0; off >>= 1)
            val += __shfl_down(val, off, 64);
        if (t == 0) s_kq = val;
    }

    // --- main pass: each thread loads 4 float4 (rows rb, rb+32, rb+64, rb+96
    //     of the 32-wide v-slice), accumulating A/Bq partials on the fly ---
    const int vc = (t & 7) * 4;      // 0..28 within slice
    const int rb = t >> 3;           // row group 0..31

    f4 s[4];
    float a0 = 0.f, a1 = 0.f, a2 = 0.f, a3 = 0.f;
    float b0 = 0.f, b1 = 0.f, b2 = 0.f, b3 = 0.f;

    #pragma unroll
    for (int i = 0; i < 4; ++i) {
        const int r = rb + 32 * i;
        s[i] = *(const f4*)(Sb + (size_t)r * DV + vc);
        const float kv = kt[r];
        const float qv = qt[r];
        a0 += s[i].x * kv;  a1 += s[i].y * kv;  a2 += s[i].z * kv;  a3 += s[i].w * kv;
        b0 += s[i].x * qv;  b1 += s[i].y * qv;  b2 += s[i].z * qv;  b3 += s[i].w * qv;
    }
    *(f4*)&apart[rb][vc] = (f4){a0, a1, a2, a3};
    *(f4*)&bpart[rb][vc] = (f4){b0, b1, b2, b3};
    __syncthreads();

    // --- finish reductions, compute delta and out (32 threads) ---
    if (t < VS) {
        float A = 0.f, Bq = 0.f;
        #pragma unroll
        for (int j = 0; j < 32; ++j) {
            A  += apart[j][t];
            Bq += bpart[j][t];
        }
        const float dlt = (vt[t] - decay * A) * bta;
        sdelta[t] = dlt;
        __builtin_nontemporal_store(decay * Bq + s_kq * dlt, &out_o[t]);
    }
    __syncthreads();

    // --- rewrite state: S' = decay*S + k[k]*delta[v] (tile still in regs) ---
    const f4 d = *(const f4*)&sdelta[vc];

    #pragma unroll
    for (int i = 0; i < 4; ++i) {
        const int r = rb + 32 * i;
        const float ktk = kt[r];
        f4 w;
        w.x = decay * s[i].x + ktk * d.x;
        w.y = decay * s[i].y + ktk * d.y;
        w.z = decay * s[i].z + ktk * d.z;
        w.w = decay * s[i].w + ktk * d.w;
        __builtin_nontemporal_store(w, (f4*)(out_S + (size_t)r * DV + vc));
    }
}

extern "C" void kernel_launch(void* const* d_in, const int* in_sizes, int n_in,
                              void* d_out, int out_size, void* d_ws, size_t ws_size,
                              hipStream_t stream) {
    const float* q    = (const float*)d_in[0];
    const float* k    = (const float*)d_in[1];
    const float* v    = (const float*)d_in[2];
    const float* g    = (const float*)d_in[3];
    const float* beta = (const float*)d_in[4];
    const float* S    = (const float*)d_in[5];
    float* out = (float*)d_out;

    const int BH = in_sizes[3];   // g has B*H elements = 2048

    s1_cell_kernel<<<BH * 4, 256, 0, stream>>>(q, k, v, g, beta, S, out, BH);
}